// Round 4
// baseline (200.817 us; speedup 1.0000x reference)
//
#include <hip/hip_runtime.h>
#include <math.h>

#define DIM 64
#define KC 32
#define NPTS 32768
#define LOG_2PI 1.8378770664093453f
#define C0 (-58.0f)   // fixed logsumexp reference: logp <= -58.81 always (logdet>=0, logw<=0)

typedef __attribute__((ext_vector_type(8))) short short8;
typedef __attribute__((ext_vector_type(4))) float float4v;

__device__ __forceinline__ unsigned short f2bf(float f) {
    unsigned u = __float_as_uint(f);
    u += 0x7FFFu + ((u >> 16) & 1u);   // RNE
    return (unsigned short)(u >> 16);
}

__device__ __forceinline__ float rdlane(float v, int l) {
    return __int_as_float(__builtin_amdgcn_readlane(__float_as_int(v), l));
}

// ============================================================================
// Prep: one WAVE (64 threads) per component k; 32 blocks. Everything in
// registers via v_readlane broadcasts (VALU pipe, SGPR operand fma):
//   lane r holds row r. Sigma = I + tril(L)tril(L)^T  ->  full-symmetric
//   right-looking Cholesky (lanes r<c compute harmless junk, never read) ->
//   M = C^{-1} by per-column forward substitution  ->  q = M mu.
// No barriers in the factorization; LDS only for the final M transpose,
// q, and MFMA B-fragment emission.
// Bpack[k]: 12 B-fragments (4 col-tiles x 3 k-tiles), element e of lane ln =
//   B[kdim=(kt*32+(ln>>4)*8+e)][col=ct*16+(ln&15)], B[j][i]=M[i][j] for j<64,
//   row 64 = -q (augmented K-tile folding the q-subtraction into the GEMM).
// cstC[k] = -0.5*(D*log2pi + logdet) + log_softmax(w)_k - C0
// ============================================================================
__global__ __launch_bounds__(64) void prep_kernel(
    const float* __restrict__ L, const float* __restrict__ mu,
    const float* __restrict__ w, short* __restrict__ Bpack,
    float* __restrict__ cstC)
{
    const int k = blockIdx.x;
    const int lane = threadIdx.x;   // 0..63
    __shared__ float M_lds[DIM][DIM + 1];
    __shared__ float qs[DIM];

    // ---- load row `lane` of tril(L) (zeros above diag) ----
    float Lr[DIM];
    {
        const float4* Lp = (const float4*)(L + (size_t)k * DIM * DIM + lane * DIM);
#pragma unroll
        for (int j4 = 0; j4 < DIM / 4; ++j4) {
            float4 v = Lp[j4];
            Lr[4 * j4 + 0] = v.x; Lr[4 * j4 + 1] = v.y;
            Lr[4 * j4 + 2] = v.z; Lr[4 * j4 + 3] = v.w;
        }
#pragma unroll
        for (int j = 0; j < DIM; ++j)
            Lr[j] = (j <= lane) ? Lr[j] : 0.f;
    }

    // ---- Sig[j] = (I + L L^T)[lane][j]; own-row zeros kill l>lane terms ----
    float Sig[DIM];
#pragma unroll
    for (int j = 0; j < DIM; ++j) {
        float s = (j == lane) ? 1.f : 0.f;
#pragma unroll
        for (int l = 0; l <= j; ++l)
            s = fmaf(Lr[l], rdlane(Lr[l], j), s);
        Sig[j] = s;
    }

    // ---- in-register right-looking Cholesky (full-symmetric update) ----
    // After step c: Sig[c] holds C[lane][c] (valid for lane >= c).
    float ld = 0.f;   // logdet accumulator (uniform across lanes)
#pragma unroll
    for (int c = 0; c < DIM; ++c) {
        float dc2 = rdlane(Sig[c], c);
        float dc  = sqrtf(dc2);
        float rdc = __builtin_amdgcn_rcpf(dc);
        ld += __logf(dc2);                 // sum log(d^2) == 2*sum log(d)
        float myc = Sig[c] * rdc;
        Sig[c] = myc;
#pragma unroll
        for (int j = c + 1; j < DIM; ++j)
            Sig[j] = fmaf(-myc, rdlane(myc, j), Sig[j]);
    }

    // ---- M = C^{-1}: lane = column; y[i] = M[i][lane] ----
    float y[DIM];
#pragma unroll
    for (int i = 0; i < DIM; ++i) {
        float s = (i == lane) ? 1.f : 0.f;
#pragma unroll
        for (int l = 0; l < i; ++l)
            s = fmaf(-rdlane(Sig[l], i), y[l], s);   // C[i][l], valid: i>=l
        float rdi = __builtin_amdgcn_rcpf(rdlane(Sig[i], i));
        float v = s * rdi;
        y[i] = (i >= lane) ? v : 0.f;                // exact zeros above diag
        M_lds[i][lane] = y[i];                        // transpose store, 2-way/free
    }
    __syncthreads();   // single wave: ~free; orders LDS write->read

    // ---- q[lane] = sum_j M[lane][j] * mu[j] (mu uniform -> s_load) ----
    {
        const float* muk = mu + k * DIM;
        float s = 0.f;
#pragma unroll
        for (int j = 0; j < DIM; ++j)
            s = fmaf(M_lds[lane][j], muk[j], s);
        qs[lane] = s;
    }
    __syncthreads();

    // ---- cst (uniform scalar math; w uniform -> s_load) ----
    {
        float wm = -3.0e38f;
#pragma unroll
        for (int i = 0; i < KC; ++i) wm = fmaxf(wm, w[i]);
        float se = 0.f;
#pragma unroll
        for (int i = 0; i < KC; ++i) se += __expf(w[i] - wm);
        float logw = w[k] - (wm + __logf(se));
        if (lane == 0)
            cstC[k] = -0.5f * (DIM * LOG_2PI + ld) + logw - C0;
    }

    // ---- emit the 12 B-fragments (single wave: ct,kt uniform; ln = lane) ----
    const int col = (lane & 15);
    const int kb = (lane >> 4) * 8;
#pragma unroll
    for (int ct = 0; ct < 4; ++ct) {
#pragma unroll
        for (int kt = 0; kt < 3; ++kt) {
            short8 v;
            if (kt < 2) {
#pragma unroll
                for (int e = 0; e < 8; ++e)
                    v[e] = (short)f2bf(M_lds[ct * 16 + col][kt * 32 + kb + e]);
            } else {
#pragma unroll
                for (int e = 0; e < 8; ++e)
                    v[e] = (short)((kb + e == 0) ? f2bf(-qs[ct * 16 + col]) : 0);
            }
            *(short8*)(Bpack + ((size_t)(k * 12 + ct * 3 + kt) * 64 + lane) * 8) = v;
        }
    }
}

// ============================================================================
// Main: wave = (row-tile of 16, k-subset of 4). 16384 waves, 4096 blocks.
// Per k: 12 MFMAs (4 col-tiles x [j0-31, j32-63, augmented -q tile]) give
// y - q directly in C-layout; maha via in-lane squares + 16-lane butterfly;
// exp(logp - C0) accumulated as a plain sum (fixed-max logsumexp).
// ============================================================================
__global__ __launch_bounds__(256, 4) void main_kernel(
    const float* __restrict__ X, const short* __restrict__ Bpack,
    const float* __restrict__ cstC, float* __restrict__ partials)
{
    const int tid = threadIdx.x;
    const int lane = tid & 63;
    const int wv = tid >> 6;
    const int w = blockIdx.x * 4 + wv;
    const int rt = w >> 3;                 // 0..2047
    const int ks = w & 7;                  // 0..7

    // A fragments from X (bf16 RNE): A[m=lane&15][k=(lane>>4)*8+e]
    const int row = rt * 16 + (lane & 15);
    const int jb = (lane >> 4) * 8;
    const float* Xr = X + row * DIM;
    short8 a0, a1;
#pragma unroll
    for (int e = 0; e < 8; ++e) {
        a0[e] = (short)f2bf(Xr[jb + e]);
        a1[e] = (short)f2bf(Xr[32 + jb + e]);
    }
    short8 a2 = (short8)0;                 // augmented tile: x_ext[64] = 1.0
    if (lane < 16) a2[0] = (short)0x3F80;  // k_local==0 lives in lanes 0..15,e=0

    const short8* Bp = (const short8*)Bpack;
    float acc = 0.f;
#pragma unroll
    for (int kk = 0; kk < 4; ++kk) {
        const int k = ks * 4 + kk;
        const short8* bk = Bp + (size_t)k * 12 * 64;
        float p0 = 0.f, p1 = 0.f, p2 = 0.f, p3 = 0.f;
#pragma unroll
        for (int ct = 0; ct < 4; ++ct) {
            short8 b0 = bk[(ct * 3 + 0) * 64 + lane];
            short8 b1 = bk[(ct * 3 + 1) * 64 + lane];
            short8 b2 = bk[(ct * 3 + 2) * 64 + lane];
            float4v c = {0.f, 0.f, 0.f, 0.f};
            c = __builtin_amdgcn_mfma_f32_16x16x32_bf16(a0, b0, c, 0, 0, 0);
            c = __builtin_amdgcn_mfma_f32_16x16x32_bf16(a1, b1, c, 0, 0, 0);
            c = __builtin_amdgcn_mfma_f32_16x16x32_bf16(a2, b2, c, 0, 0, 0);
            p0 = fmaf(c[0], c[0], p0);     // c = y - q for row (lane>>4)*4+r
            p1 = fmaf(c[1], c[1], p1);
            p2 = fmaf(c[2], c[2], p2);
            p3 = fmaf(c[3], c[3], p3);
        }
        // sum over the 16 cols held across lanes of the same group
#pragma unroll
        for (int m = 1; m <= 8; m <<= 1) {
            p0 += __shfl_xor(p0, m, 64);
            p1 += __shfl_xor(p1, m, 64);
            p2 += __shfl_xor(p2, m, 64);
            p3 += __shfl_xor(p3, m, 64);
        }
        const float cc = cstC[k];          // cst_k - C0 (wave-uniform s_load)
        acc += __expf(fmaf(-0.5f, p0, cc));
        acc += __expf(fmaf(-0.5f, p1, cc));
        acc += __expf(fmaf(-0.5f, p2, cc));
        acc += __expf(fmaf(-0.5f, p3, cc));
    }
    // groups hold disjoint rows (in-group lanes are duplicates): combine groups
    acc += __shfl_xor(acc, 16, 64);
    acc += __shfl_xor(acc, 32, 64);

    __shared__ float pm[4];
    if (lane == 0) pm[wv] = acc;
    __syncthreads();
    if (tid == 0)
        partials[blockIdx.x] = (pm[0] + pm[1]) + (pm[2] + pm[3]);
}

// ============================================================================
// Final: sum 4096 partials -> out = -(C0 + log(S))
// ============================================================================
__global__ __launch_bounds__(256) void final_kernel(
    const float* __restrict__ partials, int n, float* __restrict__ out)
{
    const int tid = threadIdx.x;
    float s = 0.f;
    for (int i = tid; i < n; i += 256) s += partials[i];
#pragma unroll
    for (int m = 1; m <= 32; m <<= 1) s += __shfl_xor(s, m, 64);
    __shared__ float pm[4];
    if ((tid & 63) == 0) pm[tid >> 6] = s;
    __syncthreads();
    if (tid == 0) out[0] = -(C0 + logf((pm[0] + pm[1]) + (pm[2] + pm[3])));
}

extern "C" void kernel_launch(void* const* d_in, const int* in_sizes, int n_in,
                              void* d_out, int out_size, void* d_ws, size_t ws_size,
                              hipStream_t stream) {
    const float* X  = (const float*)d_in[0];   // [32768,64]
    const float* mu = (const float*)d_in[1];   // [32,64]
    const float* L  = (const float*)d_in[2];   // [32,64,64]
    const float* w  = (const float*)d_in[3];   // [32]
    // d_in[4] = it (unused)

    char* ws = (char*)d_ws;
    short* Bpack = (short*)ws;                         // 32*12*64*8 bf16 = 384 KB
    float* cstC  = (float*)(ws + 32 * 12 * 64 * 8 * 2);
    float* parts = cstC + KC;                          // 4096 floats

    prep_kernel<<<KC, 64, 0, stream>>>(L, mu, w, Bpack, cstC);
    main_kernel<<<4096, 256, 0, stream>>>(X, Bpack, cstC, parts);
    final_kernel<<<1, 256, 0, stream>>>(parts, 4096, (float*)d_out);
}

// Round 5
// 139.943 us; speedup vs baseline: 1.4350x; 1.4350x over previous
//
#include <hip/hip_runtime.h>
#include <math.h>

#define DIM 64
#define KC 32
#define NPTS 32768
#define LOG_2PI 1.8378770664093453f
#define C0 (-58.0f)   // fixed logsumexp reference: logp <= -58.81 always (logdet>=0, logw<=0)
#define SW 66         // prep LDS row stride (words): even -> 8B-aligned float2 rows, bank-stride 2 (free)

typedef __attribute__((ext_vector_type(8))) short short8;
typedef __attribute__((ext_vector_type(4))) float float4v;

__device__ __forceinline__ unsigned short f2bf(float f) {
    unsigned u = __float_as_uint(f);
    u += 0x7FFFu + ((u >> 16) & 1u);   // RNE
    return (unsigned short)(u >> 16);
}

__device__ __forceinline__ float rdlane(float v, int l) {
    return __int_as_float(__builtin_amdgcn_readlane(__float_as_int(v), l));
}

// ============================================================================
// Prep: one block (256 thr = 4 waves) per component; ALL loops rolled (code
// stays < L1I; r4's 100KB unrolled body was icache-fetch-bound at 18 cyc/instr).
// P1: Sigma = I + tril(L)tril(L)^T, 4 waves (lane=row, 16 cols/wave).
// P2: wave 0, ONE rolled 64-step loop doing Cholesky AND forward-substitution
//     inverse together (shared uniform row-c reads), LDS state, stride 66.
//     Zero-init C/Y lets pair-reads round up safely (tail products hit 0).
// P3: q = M mu (wave 0), then B-fragment emission (ct = wave).
// Bpack[k]: 12 B-fragments: elem e of lane ln = B[kt*32+(ln>>4)*8+e][ct*16+(ln&15)],
//   B[j][i] = M[i][j] (j<64), augmented row 64 = -q. cstC[k] = cst_k - C0.
// ============================================================================
__global__ __launch_bounds__(256) void prep_kernel(
    const float* __restrict__ L, const float* __restrict__ mu,
    const float* __restrict__ w, short* __restrict__ Bpack,
    float* __restrict__ cstC)
{
    const int k = blockIdx.x;
    const int t = threadIdx.x;
    const int wv = t >> 6;
    const int ln = t & 63;
    __shared__ float Llds[DIM * SW];
    __shared__ float Sig[DIM * SW];
    __shared__ float Clds[DIM * SW];
    __shared__ float Ylds[DIM * SW];   // Ylds[j*SW + i] = M[i][j] (column j per row)
    __shared__ float qlds[DIM];

    // ---- P0: load tril(L); zero C and Y (backing for rounded-up pair reads)
    for (int idx = t; idx < DIM * DIM; idx += 256) {
        int r = idx >> 6, c = idx & 63;
        float v = L[(size_t)k * DIM * DIM + idx];
        Llds[r * SW + c] = (c <= r) ? v : 0.f;
    }
    for (int idx = t; idx < DIM * SW; idx += 256) {
        Clds[idx] = 0.f;
        Ylds[idx] = 0.f;
    }
    __syncthreads();

    // ---- P1: Sigma[ln][j] for j in wave's 16-col slice (valid everywhere:
    // tril zeros make full-64 sums exact; no junk anywhere in Sigma).
    {
        float Lr[DIM];
        const float2* lp = (const float2*)(Llds + ln * SW);
#pragma unroll
        for (int p = 0; p < 32; ++p) {
            float2 v = lp[p];
            Lr[2 * p] = v.x; Lr[2 * p + 1] = v.y;
        }
        for (int jj = 0; jj < 16; ++jj) {
            const int j = wv * 16 + jj;
            const float2* up = (const float2*)(Llds + j * SW);
            float a0 = 0.f, a1 = 0.f, a2 = 0.f, a3 = 0.f;
#pragma unroll
            for (int p = 0; p < 32; p += 2) {
                float2 u0 = up[p], u1 = up[p + 1];
                a0 = fmaf(Lr[2 * p], u0.x, a0);
                a1 = fmaf(Lr[2 * p + 1], u0.y, a1);
                a2 = fmaf(Lr[2 * p + 2], u1.x, a2);
                a3 = fmaf(Lr[2 * p + 3], u1.y, a3);
            }
            float s = (a0 + a1) + (a2 + a3);
            if (j == ln) s += 1.f;
            Sig[ln * SW + j] = s;
        }
    }
    __syncthreads();

    // ---- P2: merged Cholesky + inverse, wave 0, rolled
    if (wv == 0) {
        float ld2 = 0.f;   // sum log(d_c^2) = logdet (uniform)
        const float2* crow = (const float2*)(Clds + ln * SW);   // C row ln
        const float2* yrow = (const float2*)(Ylds + ln * SW);   // M column ln
        for (int c = 0; c < DIM; ++c) {
            const float2* urow = (const float2*)(Clds + c * SW);  // C row c (uniform)
            float sc0 = 0.f, sc1 = 0.f, si0 = 0.f, si1 = 0.f;
            const int np = (c + 1) >> 1;   // pairs cover l<c; tail l==c reads 0 (zero-init)
            for (int p = 0; p < np; ++p) {
                float2 cu = urow[p];
                float2 cr = crow[p];
                float2 yr = yrow[p];
                sc0 = fmaf(cr.x, cu.x, sc0);
                sc1 = fmaf(cr.y, cu.y, sc1);
                si0 = fmaf(yr.x, cu.x, si0);
                si1 = fmaf(yr.y, cu.y, si1);
            }
            // chol: s_r = Sig[r][c] - sum_{l<c} C[r][l]C[c][l]  (junk for r<c, never read)
            float schol = Sig[ln * SW + c] - (sc0 + sc1);
            // inv:  s_j = delta_{c,j} - sum_{l<c} C[c][l] M[l][j]  (valid ALL lanes)
            float sinv = ((ln == c) ? 1.f : 0.f) - (si0 + si1);
            float d2 = rdlane(schol, c);       // = C[c][c]^2 pre-sqrt; lane c valid
            ld2 += __logf(d2);
            float rd = __builtin_amdgcn_rsqf(d2);   // 1/d
            Clds[ln * SW + c] = schol * rd;         // col c of C (diag: d2*rd = d)
            float yv = sinv * rd;                   // / C[c][c]
            Ylds[ln * SW + c] = (ln <= c) ? yv : 0.f;  // exact zeros above diag of M
        }
        // q_i = sum_j M[i][j] mu[j]; lane = i
        const float* muk = mu + k * DIM;
        float qv = 0.f;
#pragma unroll 8
        for (int j = 0; j < DIM; ++j)
            qv = fmaf(Ylds[j * SW + ln], muk[j], qv);
        qlds[ln] = qv;
        if (ln == 0) {
            float wm = -3.0e38f;
            for (int i = 0; i < KC; ++i) wm = fmaxf(wm, w[i]);
            float se = 0.f;
            for (int i = 0; i < KC; ++i) se += __expf(w[i] - wm);
            float logw = w[k] - (wm + __logf(se));
            cstC[k] = -0.5f * (DIM * LOG_2PI + ld2) + logw - C0;
        }
    }
    __syncthreads();

    // ---- P3: emission; wave = col-tile ct
    {
        const int ct = wv;
        const int col = ct * 16 + (ln & 15);
        const int kb = (ln >> 4) * 8;
#pragma unroll
        for (int kt = 0; kt < 3; ++kt) {
            short8 v;
            if (kt < 2) {
#pragma unroll
                for (int e = 0; e < 8; ++e)
                    v[e] = (short)f2bf(Ylds[(kt * 32 + kb + e) * SW + col]);  // M[col][j]
            } else {
#pragma unroll
                for (int e = 0; e < 8; ++e)
                    v[e] = (short)((kb + e == 0) ? f2bf(-qlds[col]) : 0);
            }
            *(short8*)(Bpack + ((size_t)(k * 12 + ct * 3 + kt) * 64 + ln) * 8) = v;
        }
    }
}

// ============================================================================
// Main v2: block = one k-subset (4 components) x 128 rows; 2048 blocks x 256.
// Bpack slice (48 KB) staged ONCE into LDS, shared by all 4 waves (cuts L2
// B-traffic ~8x vs r4). Each wave: 32 rows (2 row-tiles) x 4 k's = 96 MFMAs.
// Fixed-reference logsumexp: acc += exp(logp - C0), plain sums all the way.
// ============================================================================
__global__ __launch_bounds__(256, 2) void main_kernel(
    const float* __restrict__ X, const float* __restrict__ Bpack,
    const float* __restrict__ cstC, float* __restrict__ partials)
{
    const int tid = threadIdx.x;
    const int lane = tid & 63;
    const int wv = tid >> 6;
    const int ks = blockIdx.x & 7;         // k in [4ks, 4ks+4)
    const int g = blockIdx.x >> 3;         // row group: 128 rows

    __shared__ float4 Bsh[3072];           // 48 KB = 4k x 12 frags x 64 lanes x 16B
    {
        const float4* Bg = (const float4*)Bpack + (size_t)ks * 3072;
#pragma unroll
        for (int it = 0; it < 12; ++it)
            Bsh[it * 256 + tid] = Bg[it * 256 + tid];
    }

    // A fragments for two row-tiles: rows r0 = base+(lane&15), r1 = r0+16
    const int rbase = g * 128 + wv * 32;
    const int jb = (lane >> 4) * 8;
    const float* Xr0 = X + (size_t)(rbase + (lane & 15)) * DIM;
    const float* Xr1 = Xr0 + 16 * DIM;
    short8 a0, a1, b0r, b1r;
#pragma unroll
    for (int e = 0; e < 8; ++e) {
        a0[e] = (short)f2bf(Xr0[jb + e]);
        a1[e] = (short)f2bf(Xr0[32 + jb + e]);
        b0r[e] = (short)f2bf(Xr1[jb + e]);
        b1r[e] = (short)f2bf(Xr1[32 + jb + e]);
    }
    short8 a2 = (short8)0;                 // augmented tile: x_ext[64] = 1.0
    if (lane < 16) a2[0] = (short)0x3F80;

    __syncthreads();

    const short8* Bs = (const short8*)Bsh;
    float acc = 0.f;
#pragma unroll
    for (int kk = 0; kk < 4; ++kk) {
        const int k = ks * 4 + kk;
        float p0 = 0.f, p1 = 0.f, p2 = 0.f, p3 = 0.f;
        float r0 = 0.f, r1 = 0.f, r2 = 0.f, r3 = 0.f;
#pragma unroll
        for (int ct = 0; ct < 4; ++ct) {
            short8 f0 = Bs[(kk * 12 + ct * 3 + 0) * 64 + lane];
            short8 f1 = Bs[(kk * 12 + ct * 3 + 1) * 64 + lane];
            short8 f2 = Bs[(kk * 12 + ct * 3 + 2) * 64 + lane];
            float4v c0 = {0.f, 0.f, 0.f, 0.f};
            c0 = __builtin_amdgcn_mfma_f32_16x16x32_bf16(a0, f0, c0, 0, 0, 0);
            c0 = __builtin_amdgcn_mfma_f32_16x16x32_bf16(a1, f1, c0, 0, 0, 0);
            c0 = __builtin_amdgcn_mfma_f32_16x16x32_bf16(a2, f2, c0, 0, 0, 0);
            float4v c1 = {0.f, 0.f, 0.f, 0.f};
            c1 = __builtin_amdgcn_mfma_f32_16x16x32_bf16(b0r, f0, c1, 0, 0, 0);
            c1 = __builtin_amdgcn_mfma_f32_16x16x32_bf16(b1r, f1, c1, 0, 0, 0);
            c1 = __builtin_amdgcn_mfma_f32_16x16x32_bf16(a2, f2, c1, 0, 0, 0);
            p0 = fmaf(c0[0], c0[0], p0); p1 = fmaf(c0[1], c0[1], p1);
            p2 = fmaf(c0[2], c0[2], p2); p3 = fmaf(c0[3], c0[3], p3);
            r0 = fmaf(c1[0], c1[0], r0); r1 = fmaf(c1[1], c1[1], r1);
            r2 = fmaf(c1[2], c1[2], r2); r3 = fmaf(c1[3], c1[3], r3);
        }
#pragma unroll
        for (int m = 1; m <= 8; m <<= 1) {
            p0 += __shfl_xor(p0, m, 64); p1 += __shfl_xor(p1, m, 64);
            p2 += __shfl_xor(p2, m, 64); p3 += __shfl_xor(p3, m, 64);
            r0 += __shfl_xor(r0, m, 64); r1 += __shfl_xor(r1, m, 64);
            r2 += __shfl_xor(r2, m, 64); r3 += __shfl_xor(r3, m, 64);
        }
        const float cc = cstC[k];          // wave-uniform s_load
        acc += __expf(fmaf(-0.5f, p0, cc)) + __expf(fmaf(-0.5f, p1, cc));
        acc += __expf(fmaf(-0.5f, p2, cc)) + __expf(fmaf(-0.5f, p3, cc));
        acc += __expf(fmaf(-0.5f, r0, cc)) + __expf(fmaf(-0.5f, r1, cc));
        acc += __expf(fmaf(-0.5f, r2, cc)) + __expf(fmaf(-0.5f, r3, cc));
    }
    // lane groups hold disjoint rows; in-group lanes are duplicates post-butterfly
    acc += __shfl_xor(acc, 16, 64);
    acc += __shfl_xor(acc, 32, 64);

    __shared__ float pm[4];
    if (lane == 0) pm[wv] = acc;
    __syncthreads();
    if (tid == 0)
        partials[blockIdx.x] = (pm[0] + pm[1]) + (pm[2] + pm[3]);
}

// ============================================================================
// Final: sum 2048 partials -> out = -(C0 + log(S))
// ============================================================================
__global__ __launch_bounds__(256) void final_kernel(
    const float* __restrict__ partials, int n, float* __restrict__ out)
{
    const int tid = threadIdx.x;
    float s = 0.f;
    for (int i = tid; i < n; i += 256) s += partials[i];
#pragma unroll
    for (int m = 1; m <= 32; m <<= 1) s += __shfl_xor(s, m, 64);
    __shared__ float pm[4];
    if ((tid & 63) == 0) pm[tid >> 6] = s;
    __syncthreads();
    if (tid == 0) out[0] = -(C0 + logf((pm[0] + pm[1]) + (pm[2] + pm[3])));
}

extern "C" void kernel_launch(void* const* d_in, const int* in_sizes, int n_in,
                              void* d_out, int out_size, void* d_ws, size_t ws_size,
                              hipStream_t stream) {
    const float* X  = (const float*)d_in[0];   // [32768,64]
    const float* mu = (const float*)d_in[1];   // [32,64]
    const float* L  = (const float*)d_in[2];   // [32,64,64]
    const float* w  = (const float*)d_in[3];   // [32]
    // d_in[4] = it (unused)

    char* ws = (char*)d_ws;
    short* Bpack = (short*)ws;                         // 32*12*64*8 bf16 = 384 KB
    float* cstC  = (float*)(ws + 32 * 12 * 64 * 8 * 2);
    float* parts = cstC + KC;                          // 2048 floats

    prep_kernel<<<KC, 256, 0, stream>>>(L, mu, w, Bpack, cstC);
    main_kernel<<<2048, 256, 0, stream>>>(X, (const float*)Bpack, cstC, parts);
    final_kernel<<<1, 256, 0, stream>>>(parts, 2048, (float*)d_out);
}

// Round 6
// 133.163 us; speedup vs baseline: 1.5081x; 1.0509x over previous
//
#include <hip/hip_runtime.h>
#include <math.h>

#define DIM 64
#define KC 32
#define NPTS 32768
#define LOG_2PI 1.8378770664093453f
#define C0 (-58.0f)   // fixed logsumexp reference: logp <= -58.81 always (logdet>=0, logw<=0)
#define SW 66         // prep LDS row stride (words): even -> 8B-aligned float2 rows

typedef __attribute__((ext_vector_type(8))) short short8;
typedef __attribute__((ext_vector_type(4))) float float4v;

__device__ __forceinline__ unsigned short f2bf(float f) {
    unsigned u = __float_as_uint(f);
    u += 0x7FFFu + ((u >> 16) & 1u);   // RNE
    return (unsigned short)(u >> 16);
}

__device__ __forceinline__ float rdlane(float v, int l) {
    return __int_as_float(__builtin_amdgcn_readlane(__float_as_int(v), l));
}

// ============================================================================
// Prep: one block (256 thr = 4 waves) per component; rolled c-loop, STATIC
// full-row inner bounds (zero-initialized C/Y tails make full-32-pair sums
// exact) so the compiler unrolls & pipelines the LDS reads — r5's dynamic
// bound serialized one ~120cyc LDS latency per PAIR (53us); static bound pays
// it once per c-step.
// P1: Sigma = I + tril(L)tril(L)^T, 4 waves. P2: wave 0, merged Cholesky +
// forward-substitution inverse, one rolled 64-step loop. P3: q, fragments.
// Bpack[k]: 12 B-fragments: elem e of lane ln = B[kt*32+(ln>>4)*8+e][ct*16+(ln&15)],
//   B[j][i] = M[i][j] (j<64), augmented row 64 = -q. cstC[k] = cst_k - C0.
// ============================================================================
__global__ __launch_bounds__(256) void prep_kernel(
    const float* __restrict__ L, const float* __restrict__ mu,
    const float* __restrict__ w, short* __restrict__ Bpack,
    float* __restrict__ cstC)
{
    const int k = blockIdx.x;
    const int t = threadIdx.x;
    const int wv = t >> 6;
    const int ln = t & 63;
    __shared__ float Llds[DIM * SW];
    __shared__ float Sig[DIM * SW];
    __shared__ float Clds[DIM * SW];
    __shared__ float Ylds[DIM * SW];   // Ylds[j*SW + i] = M[i][j]
    __shared__ float qlds[DIM];

    // ---- P0: load tril(L); zero C and Y (zero tails back the static bounds)
    for (int idx = t; idx < DIM * DIM; idx += 256) {
        int r = idx >> 6, c = idx & 63;
        float v = L[(size_t)k * DIM * DIM + idx];
        Llds[r * SW + c] = (c <= r) ? v : 0.f;
    }
    for (int idx = t; idx < DIM * SW; idx += 256) {
        Clds[idx] = 0.f;
        Ylds[idx] = 0.f;
    }
    __syncthreads();

    // ---- P1: Sigma[ln][j], 16 cols per wave (tril zeros -> full sums exact)
    {
        float Lr[DIM];
        const float2* lp = (const float2*)(Llds + ln * SW);
#pragma unroll
        for (int p = 0; p < 32; ++p) {
            float2 v = lp[p];
            Lr[2 * p] = v.x; Lr[2 * p + 1] = v.y;
        }
#pragma unroll 1
        for (int jj = 0; jj < 16; ++jj) {
            const int j = wv * 16 + jj;
            const float2* up = (const float2*)(Llds + j * SW);
            float a0 = 0.f, a1 = 0.f, a2 = 0.f, a3 = 0.f;
#pragma unroll
            for (int p = 0; p < 32; p += 2) {
                float2 u0 = up[p], u1 = up[p + 1];
                a0 = fmaf(Lr[2 * p], u0.x, a0);
                a1 = fmaf(Lr[2 * p + 1], u0.y, a1);
                a2 = fmaf(Lr[2 * p + 2], u1.x, a2);
                a3 = fmaf(Lr[2 * p + 3], u1.y, a3);
            }
            float s = (a0 + a1) + (a2 + a3);
            if (j == ln) s += 1.f;
            Sig[ln * SW + j] = s;
        }
    }
    __syncthreads();

    // ---- P2: merged Cholesky + inverse, wave 0; STATIC 32-pair inner loops.
    // Invariant at entry of step c: columns >= c of Clds and Ylds are all 0,
    // so full-row dot products equal the l<c triangular sums exactly.
    if (wv == 0) {
        float ld2 = 0.f;   // sum log(d_c^2) = logdet (uniform across lanes)
        const float2* crow = (const float2*)(Clds + ln * SW);   // C row ln
        const float2* yrow = (const float2*)(Ylds + ln * SW);   // M column ln
#pragma unroll 1
        for (int c = 0; c < DIM; ++c) {
            const float2* urow = (const float2*)(Clds + c * SW);  // C row c (uniform)
            float sc0 = 0.f, sc1 = 0.f, si0 = 0.f, si1 = 0.f;
#pragma unroll
            for (int p = 0; p < 32; ++p) {
                float2 cu = urow[p];
                float2 cr = crow[p];
                float2 yr = yrow[p];
                sc0 = fmaf(cr.x, cu.x, sc0);
                sc1 = fmaf(cr.y, cu.y, sc1);
                si0 = fmaf(yr.x, cu.x, si0);
                si1 = fmaf(yr.y, cu.y, si1);
            }
            // chol: s_r = Sig[r][c] - sum_{l<c} C[r][l]C[c][l] (junk r<c, never read)
            float schol = Sig[ln * SW + c] - (sc0 + sc1);
            // inv: s_j = delta_{c,j} - sum_{l<c} C[c][l] M[l][j] (valid all lanes)
            float sinv = ((ln == c) ? 1.f : 0.f) - (si0 + si1);
            float d2 = rdlane(schol, c);        // C[c][c]^2 pre-sqrt
            ld2 += __logf(d2);                  // off critical path
            float rd = __builtin_amdgcn_rsqf(d2);    // 1/d
            Clds[ln * SW + c] = schol * rd;          // col c of C (diag: d)
            float yv = sinv * rd;
            Ylds[ln * SW + c] = (ln <= c) ? yv : 0.f;  // exact zeros above diag
        }
        // q_i = sum_j M[i][j] mu[j]; lane = i
        const float* muk = mu + k * DIM;
        float qv = 0.f;
#pragma unroll 8
        for (int j = 0; j < DIM; ++j)
            qv = fmaf(Ylds[j * SW + ln], muk[j], qv);
        qlds[ln] = qv;
        if (ln == 0) {
            float wm = -3.0e38f;
            for (int i = 0; i < KC; ++i) wm = fmaxf(wm, w[i]);
            float se = 0.f;
            for (int i = 0; i < KC; ++i) se += __expf(w[i] - wm);
            float logw = w[k] - (wm + __logf(se));
            cstC[k] = -0.5f * (DIM * LOG_2PI + ld2) + logw - C0;
        }
    }
    __syncthreads();

    // ---- P3: emission; wave = col-tile ct
    {
        const int ct = wv;
        const int col = ct * 16 + (ln & 15);
        const int kb = (ln >> 4) * 8;
#pragma unroll
        for (int kt = 0; kt < 3; ++kt) {
            short8 v;
            if (kt < 2) {
#pragma unroll
                for (int e = 0; e < 8; ++e)
                    v[e] = (short)f2bf(Ylds[(kt * 32 + kb + e) * SW + col]);  // M[col][j]
            } else {
#pragma unroll
                for (int e = 0; e < 8; ++e)
                    v[e] = (short)((kb + e == 0) ? f2bf(-qlds[col]) : 0);
            }
            *(short8*)(Bpack + ((size_t)(k * 12 + ct * 3 + kt) * 64 + ln) * 8) = v;
        }
    }
}

// ============================================================================
// Main: block = one k-subset (4 components) x 128 rows; 2048 blocks x 256.
// Bpack slice (48 KB) staged once into LDS, shared by 4 waves. Each wave:
// 32 rows (2 row-tiles) x 4 k's = 96 MFMAs. Fixed-reference logsumexp.
// ============================================================================
__global__ __launch_bounds__(256, 2) void main_kernel(
    const float* __restrict__ X, const float* __restrict__ Bpack,
    const float* __restrict__ cstC, float* __restrict__ partials)
{
    const int tid = threadIdx.x;
    const int lane = tid & 63;
    const int wv = tid >> 6;
    const int ks = blockIdx.x & 7;         // k in [4ks, 4ks+4)
    const int g = blockIdx.x >> 3;         // row group: 128 rows

    __shared__ float4 Bsh[3072];           // 48 KB
    {
        const float4* Bg = (const float4*)Bpack + (size_t)ks * 3072;
#pragma unroll
        for (int it = 0; it < 12; ++it)
            Bsh[it * 256 + tid] = Bg[it * 256 + tid];
    }

    const int rbase = g * 128 + wv * 32;
    const int jb = (lane >> 4) * 8;
    const float* Xr0 = X + (size_t)(rbase + (lane & 15)) * DIM;
    const float* Xr1 = Xr0 + 16 * DIM;
    short8 a0, a1, b0r, b1r;
#pragma unroll
    for (int e = 0; e < 8; ++e) {
        a0[e] = (short)f2bf(Xr0[jb + e]);
        a1[e] = (short)f2bf(Xr0[32 + jb + e]);
        b0r[e] = (short)f2bf(Xr1[jb + e]);
        b1r[e] = (short)f2bf(Xr1[32 + jb + e]);
    }
    short8 a2 = (short8)0;                 // augmented tile: x_ext[64] = 1.0
    if (lane < 16) a2[0] = (short)0x3F80;

    __syncthreads();

    const short8* Bs = (const short8*)Bsh;
    float acc = 0.f;
#pragma unroll
    for (int kk = 0; kk < 4; ++kk) {
        const int k = ks * 4 + kk;
        float p0 = 0.f, p1 = 0.f, p2 = 0.f, p3 = 0.f;
        float r0 = 0.f, r1 = 0.f, r2 = 0.f, r3 = 0.f;
#pragma unroll
        for (int ct = 0; ct < 4; ++ct) {
            short8 f0 = Bs[(kk * 12 + ct * 3 + 0) * 64 + lane];
            short8 f1 = Bs[(kk * 12 + ct * 3 + 1) * 64 + lane];
            short8 f2 = Bs[(kk * 12 + ct * 3 + 2) * 64 + lane];
            float4v c0 = {0.f, 0.f, 0.f, 0.f};
            c0 = __builtin_amdgcn_mfma_f32_16x16x32_bf16(a0, f0, c0, 0, 0, 0);
            c0 = __builtin_amdgcn_mfma_f32_16x16x32_bf16(a1, f1, c0, 0, 0, 0);
            c0 = __builtin_amdgcn_mfma_f32_16x16x32_bf16(a2, f2, c0, 0, 0, 0);
            float4v c1 = {0.f, 0.f, 0.f, 0.f};
            c1 = __builtin_amdgcn_mfma_f32_16x16x32_bf16(b0r, f0, c1, 0, 0, 0);
            c1 = __builtin_amdgcn_mfma_f32_16x16x32_bf16(b1r, f1, c1, 0, 0, 0);
            c1 = __builtin_amdgcn_mfma_f32_16x16x32_bf16(a2, f2, c1, 0, 0, 0);
            p0 = fmaf(c0[0], c0[0], p0); p1 = fmaf(c0[1], c0[1], p1);
            p2 = fmaf(c0[2], c0[2], p2); p3 = fmaf(c0[3], c0[3], p3);
            r0 = fmaf(c1[0], c1[0], r0); r1 = fmaf(c1[1], c1[1], r1);
            r2 = fmaf(c1[2], c1[2], r2); r3 = fmaf(c1[3], c1[3], r3);
        }
#pragma unroll
        for (int m = 1; m <= 8; m <<= 1) {
            p0 += __shfl_xor(p0, m, 64); p1 += __shfl_xor(p1, m, 64);
            p2 += __shfl_xor(p2, m, 64); p3 += __shfl_xor(p3, m, 64);
            r0 += __shfl_xor(r0, m, 64); r1 += __shfl_xor(r1, m, 64);
            r2 += __shfl_xor(r2, m, 64); r3 += __shfl_xor(r3, m, 64);
        }
        const float cc = cstC[k];          // wave-uniform s_load
        acc += __expf(fmaf(-0.5f, p0, cc)) + __expf(fmaf(-0.5f, p1, cc));
        acc += __expf(fmaf(-0.5f, p2, cc)) + __expf(fmaf(-0.5f, p3, cc));
        acc += __expf(fmaf(-0.5f, r0, cc)) + __expf(fmaf(-0.5f, r1, cc));
        acc += __expf(fmaf(-0.5f, r2, cc)) + __expf(fmaf(-0.5f, r3, cc));
    }
    acc += __shfl_xor(acc, 16, 64);
    acc += __shfl_xor(acc, 32, 64);

    __shared__ float pm[4];
    if (lane == 0) pm[wv] = acc;
    __syncthreads();
    if (tid == 0)
        partials[blockIdx.x] = (pm[0] + pm[1]) + (pm[2] + pm[3]);
}

// ============================================================================
// Final: sum 2048 partials -> out = -(C0 + log(S))
// ============================================================================
__global__ __launch_bounds__(256) void final_kernel(
    const float* __restrict__ partials, int n, float* __restrict__ out)
{
    const int tid = threadIdx.x;
    float s = 0.f;
    for (int i = tid; i < n; i += 256) s += partials[i];
#pragma unroll
    for (int m = 1; m <= 32; m <<= 1) s += __shfl_xor(s, m, 64);
    __shared__ float pm[4];
    if ((tid & 63) == 0) pm[tid >> 6] = s;
    __syncthreads();
    if (tid == 0) out[0] = -(C0 + logf((pm[0] + pm[1]) + (pm[2] + pm[3])));
}

extern "C" void kernel_launch(void* const* d_in, const int* in_sizes, int n_in,
                              void* d_out, int out_size, void* d_ws, size_t ws_size,
                              hipStream_t stream) {
    const float* X  = (const float*)d_in[0];   // [32768,64]
    const float* mu = (const float*)d_in[1];   // [32,64]
    const float* L  = (const float*)d_in[2];   // [32,64,64]
    const float* w  = (const float*)d_in[3];   // [32]
    // d_in[4] = it (unused)

    char* ws = (char*)d_ws;
    short* Bpack = (short*)ws;                         // 32*12*64*8 bf16 = 384 KB
    float* cstC  = (float*)(ws + 32 * 12 * 64 * 8 * 2);
    float* parts = cstC + KC;                          // 2048 floats

    prep_kernel<<<KC, 256, 0, stream>>>(L, mu, w, Bpack, cstC);
    main_kernel<<<2048, 256, 0, stream>>>(X, (const float*)Bpack, cstC, parts);
    final_kernel<<<1, 256, 0, stream>>>(parts, 2048, (float*)d_out);
}